// Round 8
// baseline (522.247 us; speedup 1.0000x reference)
//
#include <hip/hip_runtime.h>
#include <stdint.h>

typedef __bf16 bf16x8 __attribute__((ext_vector_type(8)));
typedef __bf16 bf16x4 __attribute__((ext_vector_type(4)));
typedef float f32x4 __attribute__((ext_vector_type(4)));

#define BM 128
#define BN 128
#define BK 64

// Fixed problem shape (harness-constant): B=4, T=D=2048. All div/mod by
// these are compile-time shifts/masks (gfx950 has no integer divide).
constexpr int  DC  = 2048;
constexpr int  TC  = 2048;
constexpr long DDC = (long)DC * DC;          // 2^22
constexpr int  BnC = 4;
constexpr int  BDC = BnC * DC;               // 8192 = 2^13
constexpr int  CC  = 64;                     // scan chunks
constexpr int  LC  = TC / CC;                // 32
constexpr int  VW  = 4;                      // wkv d-vector width (r8)
constexpr int  NH  = BDC / VW;               // 2048 column-groups

// ---------------------------------------------------------------------------
// Fused prep: (a) f32->bf16 convert of the 4 weight matrices, (b) time-shift
// mix producing all three mixed A-matrices (bf16). Block-uniform branch.
// ---------------------------------------------------------------------------
__global__ void prep_kernel(const float* __restrict__ w0, const float* __restrict__ w1,
                            const float* __restrict__ w2, const float* __restrict__ w3,
                            __bf16* __restrict__ o0, __bf16* __restrict__ o1,
                            __bf16* __restrict__ o2, __bf16* __restrict__ o3,
                            unsigned cvtBlocks,
                            const float* __restrict__ x,
                            const float* __restrict__ mk, const float* __restrict__ mv,
                            const float* __restrict__ mr,
                            __bf16* __restrict__ ok, __bf16* __restrict__ ov,
                            __bf16* __restrict__ orr,
                            long total) {
    if (blockIdx.x < cvtBlocks) {
        long idx = ((long)blockIdx.x * blockDim.x + threadIdx.x) * 8;
        if (idx >= 4 * DDC) return;
        int w = (int)(idx >> 22);           // idx / DDC (block-uniform)
        long off = idx & (DDC - 1);         // idx % DDC
        const float* in = (w == 0) ? w0 : (w == 1) ? w1 : (w == 2) ? w2 : w3;
        __bf16* out     = (w == 0) ? o0 : (w == 1) ? o1 : (w == 2) ? o2 : o3;
        f32x4 a = *(const f32x4*)(in + off);
        f32x4 b = *(const f32x4*)(in + off + 4);
        bf16x8 o;
#pragma unroll
        for (int i = 0; i < 4; ++i) { o[i] = (__bf16)a[i]; o[i + 4] = (__bf16)b[i]; }
        *(bf16x8*)(out + off) = o;
    } else {
        long idx = ((long)(blockIdx.x - cvtBlocks) * blockDim.x + threadIdx.x) * 8;
        if (idx >= total) return;
        int d = (int)(idx & (DC - 1));      // idx % D
        long bt = idx >> 11;                // idx / D
        int t = (int)(bt & (TC - 1));       // bt % T

        f32x4 x0 = *(const f32x4*)(x + idx);
        f32x4 x1 = *(const f32x4*)(x + idx + 4);
        f32x4 l0 = {}, l1 = {};
        if (t != 0) {
            l0 = *(const f32x4*)(x + idx - DC);
            l1 = *(const f32x4*)(x + idx - DC + 4);
        }
        const float* mw[3] = {mk, mv, mr};
        __bf16* ow[3] = {ok, ov, orr};
#pragma unroll
        for (int s = 0; s < 3; ++s) {
            f32x4 m0 = *(const f32x4*)(mw[s] + d);
            f32x4 m1 = *(const f32x4*)(mw[s] + d + 4);
            bf16x8 o;
#pragma unroll
            for (int i = 0; i < 4; ++i) {
                o[i]     = (__bf16)(x0[i] * m0[i] + l0[i] * (1.0f - m0[i]));
                o[i + 4] = (__bf16)(x1[i] * m1[i] + l1[i] * (1.0f - m1[i]));
            }
            *(bf16x8*)(ow[s] + idx) = o;
        }
    }
}

// ---------------------------------------------------------------------------
// GEMM body: m97-ladder 128x128 structure + T1 XCD swizzle + (256,4) bounds
// (r7, verified 1080 TF / 127 us for the bt2 pair). Structure frozen --
// pipeline rewrites (r1/r3/r4) all measured slower.
// ---------------------------------------------------------------------------
template <typename CT>
__device__ __attribute__((always_inline))
void gemm_body(const __bf16* __restrict__ A, const __bf16* __restrict__ Bt,
               CT* __restrict__ C, int M, int N, int K) {
    __shared__ __align__(16) __bf16 sA[BM * BK];
    __shared__ __align__(16) __bf16 sB[BN * BK];

    const int tid  = threadIdx.x;
    const int lane = tid & 63;
    const int wave = tid >> 6;

    // T1: XCD-aware bijective swizzle; grid is always (16, 64) here.
    const int id  = blockIdx.y * 16 + blockIdx.x;
    const int wg  = (id & 7) * 128 + (id >> 3);     // nwg=1024
    const int bx  = wg & 15;
    const int by  = wg >> 4;
    const int m0 = by * BM;
    const int n0 = bx * BN;

    const int wm = (wave & 1) * 64;
    const int wn = (wave >> 1) * 64;

    const int l8 = lane >> 3;
    const int c8 = lane & 7;
    const int cg = c8 ^ l8;

    const int q  = lane >> 4;
    const int ml = lane & 15;

    f32x4 acc[4][4] = {};

    for (int k0 = 0; k0 < K; k0 += BK) {
#pragma unroll
        for (int i = 0; i < 4; ++i) {
            const int cl  = wave * 4 + i;
            const int row = cl * 8 + l8;
            const __bf16* gA = A  + (long)(m0 + row) * K + (k0 + cg * 8);
            const __bf16* gB = Bt + (long)(n0 + row) * K + (k0 + cg * 8);
            __builtin_amdgcn_global_load_lds(
                (const __attribute__((address_space(1))) void*)gA,
                (__attribute__((address_space(3))) void*)(sA + cl * 512), 16, 0, 0);
            __builtin_amdgcn_global_load_lds(
                (const __attribute__((address_space(1))) void*)gB,
                (__attribute__((address_space(3))) void*)(sB + cl * 512), 16, 0, 0);
        }
        __syncthreads();

#pragma unroll
        for (int kk = 0; kk < BK; kk += 32) {
            bf16x8 af[4], bfr[4];
#pragma unroll
            for (int i = 0; i < 4; ++i) {
                int row = wm + i * 16 + ml;
                int cl  = ((kk >> 3) + q) ^ (row & 7);
                af[i] = *(const bf16x8*)(sA + row * BK + cl * 8);
            }
#pragma unroll
            for (int j = 0; j < 4; ++j) {
                int row = wn + j * 16 + ml;
                int cl  = ((kk >> 3) + q) ^ (row & 7);
                bfr[j] = *(const bf16x8*)(sB + row * BK + cl * 8);
            }
#pragma unroll
            for (int i = 0; i < 4; ++i)
#pragma unroll
                for (int j = 0; j < 4; ++j)
                    acc[i][j] = __builtin_amdgcn_mfma_f32_16x16x32_bf16(
                        af[i], bfr[j], acc[i][j], 0, 0, 0);
        }
        __syncthreads();
    }

#pragma unroll
    for (int i = 0; i < 4; ++i)
#pragma unroll
        for (int j = 0; j < 4; ++j)
#pragma unroll
            for (int rg = 0; rg < 4; ++rg) {
                int row = m0 + wm + i * 16 + q * 4 + rg;
                int col = n0 + wn + j * 16 + ml;
                C[(long)row * N + col] = (CT)acc[i][j][rg];
            }
}

template <typename CT>
__global__ __launch_bounds__(256, 4)
void gemm_bt(const __bf16* __restrict__ A, const __bf16* __restrict__ Bt,
             CT* __restrict__ C, int M, int N, int K) {
    gemm_body<CT>(A, Bt, C, M, N, K);
}

// z-batched pair (v and r GEMMs), both bf16 outputs (same instantiation).
__global__ __launch_bounds__(256, 4)
void gemm_bt2(const __bf16* __restrict__ A0, const __bf16* __restrict__ A1,
              const __bf16* __restrict__ B0, const __bf16* __restrict__ B1,
              __bf16* __restrict__ C0, __bf16* __restrict__ C1,
              int M, int N, int K) {
    if (blockIdx.z == 0) gemm_body<__bf16>(A0, B0, C0, M, N, K);
    else                 gemm_body<__bf16>(A1, B1, C1, M, N, K);
}

// ---------------------------------------------------------------------------
// Chunk-parallel WKV scan, C=64 (L=32), separate exclusive-prefix combine.
// r8: x4 d-vectorization (G13 / m146 mechanism: scalar bf16 streaming caps
// ~2.35 TB/s; vectorized reaches ~4.9). Each thread owns 4 adjacent d:
// k loads f32x4 (16B/lane), v/r loads bf16x4 (8B/lane), out stores bf16x4.
// Same per-element arithmetic and order -> bitwise-identical numerics.
// ---------------------------------------------------------------------------
__global__ void wkv_pass1(const float* __restrict__ kk, const __bf16* __restrict__ vv,
                          const float* __restrict__ td,
                          float* __restrict__ al, float* __restrict__ bl,
                          float* __restrict__ el) {
    int gid = blockIdx.x * blockDim.x + threadIdx.x;
    if (gid >= NH * CC) return;
    int c  = gid >> 11;                 // gid / NH (block-uniform: 2048 % 256 == 0)
    int h  = gid & (NH - 1);
    int bd = h * VW;
    int b  = bd >> 11;                  // bd / D
    int d  = bd & (DC - 1);

    f32x4 w, alpha = {}, beta = {};
    f32x4 eps = {-1e30f, -1e30f, -1e30f, -1e30f};
#pragma unroll
    for (int i = 0; i < VW; ++i) w[i] = __expf(td[d + i]);

    long base = ((long)b * TC + (long)c * LC) * DC + d;

    const int P = 4;
    f32x4 kb0[P], kb1[P];
    bf16x4 vb0[P], vb1[P];

    auto step = [&](const f32x4& kt, const bf16x4& vt) {
#pragma unroll
        for (int i = 0; i < VW; ++i) {
            float ww2  = eps[i] - w[i];
            float tau2 = fmaxf(ww2, kt[i]);
            float e1b  = __expf(ww2 - tau2);
            float e2b  = __expf(kt[i] - tau2);
            alpha[i] = e1b * alpha[i] + e2b * (float)vt[i];
            beta[i]  = e1b * beta[i] + e2b;
            eps[i]   = tau2;
        }
    };

#pragma unroll
    for (int j = 0; j < P; ++j) {
        long o = base + (long)j * DC;
        kb0[j] = *(const f32x4*)(kk + o);
        vb0[j] = *(const bf16x4*)(vv + o);
    }
    for (int t0 = 0; t0 < LC; t0 += 2 * P) {
#pragma unroll
        for (int j = 0; j < P; ++j) {
            long o = base + (long)(t0 + P + j) * DC;
            kb1[j] = *(const f32x4*)(kk + o);
            vb1[j] = *(const bf16x4*)(vv + o);
        }
#pragma unroll
        for (int j = 0; j < P; ++j) step(kb0[j], vb0[j]);
        if (t0 + 2 * P < LC) {
#pragma unroll
            for (int j = 0; j < P; ++j) {
                long o = base + (long)(t0 + 2 * P + j) * DC;
                kb0[j] = *(const f32x4*)(kk + o);
                vb0[j] = *(const bf16x4*)(vv + o);
            }
        }
#pragma unroll
        for (int j = 0; j < P; ++j) step(kb1[j], vb1[j]);
    }
    int sidx = c * BDC + bd;
    *(f32x4*)(al + sidx) = alpha;
    *(f32x4*)(bl + sidx) = beta;
    *(f32x4*)(el + sidx) = eps;
}

// Exclusive prefix over chunks, in place. One thread per (b,d) column,
// sequential over C chunks (coalesced across bd), P-batched loads.
__global__ void wkv_combine(float* __restrict__ al, float* __restrict__ bl,
                            float* __restrict__ el,
                            const float* __restrict__ td) {
    int bd = blockIdx.x * blockDim.x + threadIdx.x;
    if (bd >= BDC) return;
    int d = bd & (DC - 1);
    float wL = __expf(td[d]) * (float)LC;

    float pa = 0.f, pb = 0.f, pe = -1e30f;
    const int P = 8;
    float la[P], lb[P], le[P];
    for (int c0 = 0; c0 < CC; c0 += P) {
#pragma unroll
        for (int j = 0; j < P; ++j) {
            int idx = (c0 + j) * BDC + bd;
            la[j] = al[idx]; lb[j] = bl[idx]; le[j] = el[idx];
        }
#pragma unroll
        for (int j = 0; j < P; ++j) {
            int idx = (c0 + j) * BDC + bd;
            al[idx] = pa; bl[idx] = pb; el[idx] = pe;   // exclusive prefix
            float ed  = pe - wL;
            float tau = fmaxf(ed, le[j]);
            float e1  = __expf(ed - tau);
            float e2  = __expf(le[j] - tau);
            pa = pa * e1 + la[j] * e2;
            pb = pb * e1 + lb[j] * e2;
            pe = tau;
        }
    }
}

__global__ void wkv_pass2(const float* __restrict__ kk, const __bf16* __restrict__ vv,
                          const __bf16* __restrict__ rr,
                          const float* __restrict__ td, const float* __restrict__ tf,
                          const float* __restrict__ al, const float* __restrict__ bl,
                          const float* __restrict__ el,
                          __bf16* __restrict__ out) {
    int gid = blockIdx.x * blockDim.x + threadIdx.x;
    if (gid >= NH * CC) return;
    int c  = gid >> 11;                 // gid / NH (block-uniform)
    int h  = gid & (NH - 1);
    int bd = h * VW;
    int b  = bd >> 11;
    int d  = bd & (DC - 1);

    f32x4 u, w;
#pragma unroll
    for (int i = 0; i < VW; ++i) {
        u[i] = tf[d + i];
        w[i] = __expf(td[d + i]);
    }

    // inbound state precomputed by wkv_combine (exclusive prefix)
    int sidx = c * BDC + bd;
    f32x4 alpha = *(const f32x4*)(al + sidx);
    f32x4 beta  = *(const f32x4*)(bl + sidx);
    f32x4 eps   = *(const f32x4*)(el + sidx);

    long base = ((long)b * TC + (long)c * LC) * DC + d;

    const int P = 4;
    f32x4 kb0[P], kb1[P];
    bf16x4 vb0[P], vb1[P], rb0[P], rb1[P];

    auto step = [&](const f32x4& kt, const bf16x4& vt, const bf16x4& rt, int tIdx) {
        bf16x4 ov;
#pragma unroll
        for (int i = 0; i < VW; ++i) {
            float ww  = u[i] + kt[i];
            float tau = fmaxf(eps[i], ww);
            float e1  = __expf(eps[i] - tau);
            float e2  = __expf(ww - tau);
            float num = e1 * alpha[i] + e2 * (float)vt[i];
            float den = e1 * beta[i] + e2;
            float o_  = num * __builtin_amdgcn_rcpf(den);
            float ww2  = eps[i] - w[i];
            float tau2 = fmaxf(ww2, kt[i]);
            float e1b  = __expf(ww2 - tau2);
            float e2b  = __expf(kt[i] - tau2);
            alpha[i] = e1b * alpha[i] + e2b * (float)vt[i];
            beta[i]  = e1b * beta[i] + e2b;
            eps[i]   = tau2;
            float sr = __builtin_amdgcn_rcpf(1.0f + __expf(-(float)rt[i]));
            ov[i] = (__bf16)(o_ * sr);
        }
        *(bf16x4*)(out + base + (long)tIdx * DC) = ov;
    };

#pragma unroll
    for (int j = 0; j < P; ++j) {
        long o = base + (long)j * DC;
        kb0[j] = *(const f32x4*)(kk + o);
        vb0[j] = *(const bf16x4*)(vv + o);
        rb0[j] = *(const bf16x4*)(rr + o);
    }
    for (int t0 = 0; t0 < LC; t0 += 2 * P) {
#pragma unroll
        for (int j = 0; j < P; ++j) {
            long o = base + (long)(t0 + P + j) * DC;
            kb1[j] = *(const f32x4*)(kk + o);
            vb1[j] = *(const bf16x4*)(vv + o);
            rb1[j] = *(const bf16x4*)(rr + o);
        }
#pragma unroll
        for (int j = 0; j < P; ++j) step(kb0[j], vb0[j], rb0[j], t0 + j);
        if (t0 + 2 * P < LC) {
#pragma unroll
            for (int j = 0; j < P; ++j) {
                long o = base + (long)(t0 + 2 * P + j) * DC;
                kb0[j] = *(const f32x4*)(kk + o);
                vb0[j] = *(const bf16x4*)(vv + o);
                rb0[j] = *(const bf16x4*)(rr + o);
            }
        }
#pragma unroll
        for (int j = 0; j < P; ++j) step(kb1[j], vb1[j], rb1[j], t0 + P + j);
    }
}

// ---------------------------------------------------------------------------
extern "C" void kernel_launch(void* const* d_in, const int* in_sizes, int n_in,
                              void* d_out, int out_size, void* d_ws, size_t ws_size,
                              hipStream_t stream) {
    const float* x  = (const float*)d_in[0];
    const float* td = (const float*)d_in[1];
    const float* tf = (const float*)d_in[2];
    const float* mk = (const float*)d_in[3];
    const float* mv = (const float*)d_in[4];
    const float* mr = (const float*)d_in[5];
    const float* Wk = (const float*)d_in[6];
    const float* Wv = (const float*)d_in[7];
    const float* Wr = (const float*)d_in[8];
    const float* Wo = (const float*)d_in[9];
    float* out = (float*)d_out;

    const int D = DC;
    const int T = TC;
    const long total = (long)in_sizes[0];         // B*T*D = 16.7M
    const int M = BnC * T;                        // 8192
    const long DD = DDC;
    const int S = BDC * CC;

    // --- workspace layout (aliasing relies on stream order) ---
    char* p = (char*)d_ws;
    __bf16* xmk = (__bf16*)p;            p += total * 2;   // dead after gemm_k
    __bf16* xmv = (__bf16*)p;            p += total * 2;   // dead after gemm_bt2
    __bf16* xmr = (__bf16*)p;            p += total * 2;   // dead after gemm_bt2
    __bf16* wkb = (__bf16*)p;            p += DD * 2;      // dead after gemm_k
    __bf16* wvb = (__bf16*)p;            p += DD * 2;      // dead after gemm_bt2
    __bf16* wrb = (__bf16*)p;            p += DD * 2;      // dead after gemm_bt2
    __bf16* wob = (__bf16*)p;            p += DD * 2;      // live till end
    __bf16* vb  = (__bf16*)p;            p += total * 2;
    __bf16* rb  = (__bf16*)p;            p += total * 2;

    float*  kf = (float*)xmv;            // 64 MB over dead xmv+xmr
    __bf16* xo = xmk;                    // pass2 output over dead xmk
    float*  st = (float*)wkb;            // 6.3 MB scan state over dead wkb
    float *al = st, *bl = st + S, *el = st + 2 * S;

    unsigned cvtBlocks = (unsigned)((4 * DD / 8 + 255) / 256);
    unsigned mixBlocks = (unsigned)((total / 8 + 255) / 256);
    dim3 prepGrid(cvtBlocks + mixBlocks);
    dim3 gemmGrid(D / BN, M / BM);                // (16, 64)
    dim3 gemm2Grid(D / BN, M / BM, 2);
    dim3 p12Grid((NH * CC + 255) / 256);          // 512 blocks
    dim3 cmbGrid((BDC + 255) / 256);              // 32 blocks

    prep_kernel<<<prepGrid, 256, 0, stream>>>(Wk, Wv, Wr, Wo, wkb, wvb, wrb, wob,
                                              cvtBlocks,
                                              x, mk, mv, mr, xmk, xmv, xmr,
                                              total);

    // v and r GEMMs first (they consume xmv/xmr, freeing the space kf reuses)
    gemm_bt2<<<gemm2Grid, 256, 0, stream>>>(xmv, xmr, wvb, wrb, vb, rb, M, D, D);
    gemm_bt<float><<<gemmGrid, 256, 0, stream>>>(xmk, wkb, kf, M, D, D);

    wkv_pass1<<<p12Grid, 256, 0, stream>>>(kf, vb, td, al, bl, el);
    wkv_combine<<<cmbGrid, 256, 0, stream>>>(al, bl, el, td);
    wkv_pass2<<<p12Grid, 256, 0, stream>>>(kf, vb, rb, td, tf, al, bl, el, xo);

    gemm_bt<float><<<gemmGrid, 256, 0, stream>>>(xo, wob, out, M, D, D);
}

// Round 9
// 510.884 us; speedup vs baseline: 1.0222x; 1.0222x over previous
//
#include <hip/hip_runtime.h>
#include <stdint.h>

typedef __bf16 bf16x8 __attribute__((ext_vector_type(8)));
typedef float f32x4 __attribute__((ext_vector_type(4)));

#define BM 128
#define BN 128
#define BK 64

// Fixed problem shape (harness-constant): B=4, T=D=2048. All div/mod by
// these are compile-time shifts/masks (gfx950 has no integer divide).
constexpr int  DC  = 2048;
constexpr int  TC  = 2048;
constexpr long DDC = (long)DC * DC;          // 2^22
constexpr int  BnC = 4;
constexpr int  BDC = BnC * DC;               // 8192 = 2^13
constexpr int  CC  = 64;                     // scan chunks
constexpr int  LC  = TC / CC;                // 32

// ---------------------------------------------------------------------------
// Fused prep: (a) f32->bf16 convert of the 4 weight matrices, (b) time-shift
// mix producing all three mixed A-matrices (bf16). Block-uniform branch.
// ---------------------------------------------------------------------------
__global__ void prep_kernel(const float* __restrict__ w0, const float* __restrict__ w1,
                            const float* __restrict__ w2, const float* __restrict__ w3,
                            __bf16* __restrict__ o0, __bf16* __restrict__ o1,
                            __bf16* __restrict__ o2, __bf16* __restrict__ o3,
                            unsigned cvtBlocks,
                            const float* __restrict__ x,
                            const float* __restrict__ mk, const float* __restrict__ mv,
                            const float* __restrict__ mr,
                            __bf16* __restrict__ ok, __bf16* __restrict__ ov,
                            __bf16* __restrict__ orr,
                            long total) {
    if (blockIdx.x < cvtBlocks) {
        long idx = ((long)blockIdx.x * blockDim.x + threadIdx.x) * 8;
        if (idx >= 4 * DDC) return;
        int w = (int)(idx >> 22);           // idx / DDC (block-uniform)
        long off = idx & (DDC - 1);         // idx % DDC
        const float* in = (w == 0) ? w0 : (w == 1) ? w1 : (w == 2) ? w2 : w3;
        __bf16* out     = (w == 0) ? o0 : (w == 1) ? o1 : (w == 2) ? o2 : o3;
        f32x4 a = *(const f32x4*)(in + off);
        f32x4 b = *(const f32x4*)(in + off + 4);
        bf16x8 o;
#pragma unroll
        for (int i = 0; i < 4; ++i) { o[i] = (__bf16)a[i]; o[i + 4] = (__bf16)b[i]; }
        *(bf16x8*)(out + off) = o;
    } else {
        long idx = ((long)(blockIdx.x - cvtBlocks) * blockDim.x + threadIdx.x) * 8;
        if (idx >= total) return;
        int d = (int)(idx & (DC - 1));      // idx % D
        long bt = idx >> 11;                // idx / D
        int t = (int)(bt & (TC - 1));       // bt % T

        f32x4 x0 = *(const f32x4*)(x + idx);
        f32x4 x1 = *(const f32x4*)(x + idx + 4);
        f32x4 l0 = {}, l1 = {};
        if (t != 0) {
            l0 = *(const f32x4*)(x + idx - DC);
            l1 = *(const f32x4*)(x + idx - DC + 4);
        }
        const float* mw[3] = {mk, mv, mr};
        __bf16* ow[3] = {ok, ov, orr};
#pragma unroll
        for (int s = 0; s < 3; ++s) {
            f32x4 m0 = *(const f32x4*)(mw[s] + d);
            f32x4 m1 = *(const f32x4*)(mw[s] + d + 4);
            bf16x8 o;
#pragma unroll
            for (int i = 0; i < 4; ++i) {
                o[i]     = (__bf16)(x0[i] * m0[i] + l0[i] * (1.0f - m0[i]));
                o[i + 4] = (__bf16)(x1[i] * m1[i] + l1[i] * (1.0f - m1[i]));
            }
            *(bf16x8*)(ow[s] + idx) = o;
        }
    }
}

// ---------------------------------------------------------------------------
// GEMM body: m97-ladder 128x128 structure + T1 XCD swizzle + (256,4) bounds
// (r7, verified 1080 TF / 127 us for the bt2 pair). Structure frozen --
// pipeline rewrites (r1/r3/r4) all measured slower.
// LDS passed in from the __global__ wrapper (r4 trick) so gemm3's two
// template instantiations share one 32 KiB pair.
// ---------------------------------------------------------------------------
template <typename CT>
__device__ __attribute__((always_inline))
void gemm_body(const __bf16* __restrict__ A, const __bf16* __restrict__ Bt,
               CT* __restrict__ C, int M, int N, int K,
               __bf16* sA, __bf16* sB) {
    const int tid  = threadIdx.x;
    const int lane = tid & 63;
    const int wave = tid >> 6;

    // T1: XCD-aware bijective swizzle; grid is always (16, 64) per z-slice.
    const int id  = blockIdx.y * 16 + blockIdx.x;
    const int wg  = (id & 7) * 128 + (id >> 3);     // nwg=1024
    const int bx  = wg & 15;
    const int by  = wg >> 4;
    const int m0 = by * BM;
    const int n0 = bx * BN;

    const int wm = (wave & 1) * 64;
    const int wn = (wave >> 1) * 64;

    const int l8 = lane >> 3;
    const int c8 = lane & 7;
    const int cg = c8 ^ l8;

    const int q  = lane >> 4;
    const int ml = lane & 15;

    f32x4 acc[4][4] = {};

    for (int k0 = 0; k0 < K; k0 += BK) {
#pragma unroll
        for (int i = 0; i < 4; ++i) {
            const int cl  = wave * 4 + i;
            const int row = cl * 8 + l8;
            const __bf16* gA = A  + (long)(m0 + row) * K + (k0 + cg * 8);
            const __bf16* gB = Bt + (long)(n0 + row) * K + (k0 + cg * 8);
            __builtin_amdgcn_global_load_lds(
                (const __attribute__((address_space(1))) void*)gA,
                (__attribute__((address_space(3))) void*)(sA + cl * 512), 16, 0, 0);
            __builtin_amdgcn_global_load_lds(
                (const __attribute__((address_space(1))) void*)gB,
                (__attribute__((address_space(3))) void*)(sB + cl * 512), 16, 0, 0);
        }
        __syncthreads();

#pragma unroll
        for (int kk = 0; kk < BK; kk += 32) {
            bf16x8 af[4], bfr[4];
#pragma unroll
            for (int i = 0; i < 4; ++i) {
                int row = wm + i * 16 + ml;
                int cl  = ((kk >> 3) + q) ^ (row & 7);
                af[i] = *(const bf16x8*)(sA + row * BK + cl * 8);
            }
#pragma unroll
            for (int j = 0; j < 4; ++j) {
                int row = wn + j * 16 + ml;
                int cl  = ((kk >> 3) + q) ^ (row & 7);
                bfr[j] = *(const bf16x8*)(sB + row * BK + cl * 8);
            }
#pragma unroll
            for (int i = 0; i < 4; ++i)
#pragma unroll
                for (int j = 0; j < 4; ++j)
                    acc[i][j] = __builtin_amdgcn_mfma_f32_16x16x32_bf16(
                        af[i], bfr[j], acc[i][j], 0, 0, 0);
        }
        __syncthreads();
    }

#pragma unroll
    for (int i = 0; i < 4; ++i)
#pragma unroll
        for (int j = 0; j < 4; ++j)
#pragma unroll
            for (int rg = 0; rg < 4; ++rg) {
                int row = m0 + wm + i * 16 + q * 4 + rg;
                int col = n0 + wn + j * 16 + ml;
                C[(long)row * N + col] = (CT)acc[i][j][rg];
            }
}

template <typename CT>
__global__ __launch_bounds__(256, 4)
void gemm_bt(const __bf16* __restrict__ A, const __bf16* __restrict__ Bt,
             CT* __restrict__ C, int M, int N, int K) {
    __shared__ __align__(16) __bf16 sA[BM * BK];
    __shared__ __align__(16) __bf16 sB[BN * BK];
    gemm_body<CT>(A, Bt, C, M, N, K, sA, sB);
}

// r9: z-batched TRIPLE -- v, r (bf16 out) + k (f32 out) in one launch.
// Removes one launch boundary and lets k-blocks backfill the v/r tail.
// Shared LDS declared once (only one branch runs per block). kf must NOT
// alias xmv/xmr here (k runs concurrently with v/r) -> kf lives in d_out.
__global__ __launch_bounds__(256, 4)
void gemm3(const __bf16* __restrict__ Av, const __bf16* __restrict__ Ar,
           const __bf16* __restrict__ Ak,
           const __bf16* __restrict__ Bv, const __bf16* __restrict__ Br,
           const __bf16* __restrict__ Bk,
           __bf16* __restrict__ Cv, __bf16* __restrict__ Cr,
           float* __restrict__ Ck, int M, int N, int K) {
    __shared__ __align__(16) __bf16 sA[BM * BK];
    __shared__ __align__(16) __bf16 sB[BN * BK];
    if (blockIdx.z == 0)      gemm_body<__bf16>(Av, Bv, Cv, M, N, K, sA, sB);
    else if (blockIdx.z == 1) gemm_body<__bf16>(Ar, Br, Cr, M, N, K, sA, sB);
    else                      gemm_body<float>(Ak, Bk, Ck, M, N, K, sA, sB);
}

// ---------------------------------------------------------------------------
// Chunk-parallel WKV scan, C=64 (L=32), separate exclusive-prefix combine.
// r7 scalar form restored -- r8's x4 d-vectorization cut TLP 4x and
// regressed 27 us (loads were already wave-coalesced; these kernels are
// TLP/latency-bound, not load-width-bound).
// ---------------------------------------------------------------------------
__global__ void wkv_pass1(const float* __restrict__ kk, const __bf16* __restrict__ vv,
                          const float* __restrict__ td,
                          float* __restrict__ al, float* __restrict__ bl,
                          float* __restrict__ el) {
    int gid = blockIdx.x * blockDim.x + threadIdx.x;
    if (gid >= BDC * CC) return;
    int c  = gid >> 13;                 // gid / BD
    int bd = gid & (BDC - 1);
    int b  = bd >> 11;                  // bd / D
    int d  = bd & (DC - 1);

    float w = __expf(td[d]);
    float alpha = 0.f, beta = 0.f, eps = -1e30f;
    long base = ((long)b * TC + (long)c * LC) * DC + d;

    const int P = 8;
    float kb0[P], vb0[P], kb1[P], vb1[P];

    auto step = [&](float kt, float vt) {
        float ww2  = eps - w;
        float tau2 = fmaxf(ww2, kt);
        float e1b  = __expf(ww2 - tau2);
        float e2b  = __expf(kt - tau2);
        alpha = e1b * alpha + e2b * vt;
        beta  = e1b * beta + e2b;
        eps   = tau2;
    };

#pragma unroll
    for (int j = 0; j < P; ++j) {
        long o = base + (long)j * DC;
        kb0[j] = kk[o]; vb0[j] = (float)vv[o];
    }
    for (int t0 = 0; t0 < LC; t0 += 2 * P) {
#pragma unroll
        for (int j = 0; j < P; ++j) {
            long o = base + (long)(t0 + P + j) * DC;
            kb1[j] = kk[o]; vb1[j] = (float)vv[o];
        }
#pragma unroll
        for (int j = 0; j < P; ++j) step(kb0[j], vb0[j]);
        if (t0 + 2 * P < LC) {
#pragma unroll
            for (int j = 0; j < P; ++j) {
                long o = base + (long)(t0 + 2 * P + j) * DC;
                kb0[j] = kk[o]; vb0[j] = (float)vv[o];
            }
        }
#pragma unroll
        for (int j = 0; j < P; ++j) step(kb1[j], vb1[j]);
    }
    al[gid] = alpha; bl[gid] = beta; el[gid] = eps;
}

// Exclusive prefix over chunks, in place. One thread per (b,d) column,
// sequential over C chunks (coalesced across bd), P-batched loads.
__global__ void wkv_combine(float* __restrict__ al, float* __restrict__ bl,
                            float* __restrict__ el,
                            const float* __restrict__ td) {
    int bd = blockIdx.x * blockDim.x + threadIdx.x;
    if (bd >= BDC) return;
    int d = bd & (DC - 1);
    float wL = __expf(td[d]) * (float)LC;

    float pa = 0.f, pb = 0.f, pe = -1e30f;
    const int P = 8;
    float la[P], lb[P], le[P];
    for (int c0 = 0; c0 < CC; c0 += P) {
#pragma unroll
        for (int j = 0; j < P; ++j) {
            int idx = (c0 + j) * BDC + bd;
            la[j] = al[idx]; lb[j] = bl[idx]; le[j] = el[idx];
        }
#pragma unroll
        for (int j = 0; j < P; ++j) {
            int idx = (c0 + j) * BDC + bd;
            al[idx] = pa; bl[idx] = pb; el[idx] = pe;   // exclusive prefix
            float ed  = pe - wL;
            float tau = fmaxf(ed, le[j]);
            float e1  = __expf(ed - tau);
            float e2  = __expf(le[j] - tau);
            pa = pa * e1 + la[j] * e2;
            pb = pb * e1 + lb[j] * e2;
            pe = tau;
        }
    }
}

__global__ void wkv_pass2(const float* __restrict__ kk, const __bf16* __restrict__ vv,
                          const __bf16* __restrict__ rr,
                          const float* __restrict__ td, const float* __restrict__ tf,
                          const float* __restrict__ al, const float* __restrict__ bl,
                          const float* __restrict__ el,
                          __bf16* __restrict__ out) {
    int gid = blockIdx.x * blockDim.x + threadIdx.x;
    if (gid >= BDC * CC) return;
    int c  = gid >> 13;                 // gid / BD (block-uniform)
    int bd = gid & (BDC - 1);
    int b  = bd >> 11;
    int d  = bd & (DC - 1);

    float u = tf[d];
    float w = __expf(td[d]);

    // inbound state precomputed by wkv_combine (exclusive prefix)
    float alpha = al[gid], beta = bl[gid], eps = el[gid];

    long base = ((long)b * TC + (long)c * LC) * DC + d;

    const int P = 8;
    float kb0[P], vb0[P], rb0[P], kb1[P], vb1[P], rb1[P];

    auto step = [&](float kt, float vt, float rt, int tIdx) {
        float ww  = u + kt;
        float tau = fmaxf(eps, ww);
        float e1  = __expf(eps - tau);
        float e2  = __expf(ww - tau);
        float num = e1 * alpha + e2 * vt;
        float den = e1 * beta + e2;
        float o_  = num * __builtin_amdgcn_rcpf(den);
        float ww2  = eps - w;
        float tau2 = fmaxf(ww2, kt);
        float e1b  = __expf(ww2 - tau2);
        float e2b  = __expf(kt - tau2);
        alpha = e1b * alpha + e2b * vt;
        beta  = e1b * beta + e2b;
        eps   = tau2;
        float sr = __builtin_amdgcn_rcpf(1.0f + __expf(-rt));
        out[base + (long)tIdx * DC] = (__bf16)(o_ * sr);
    };

#pragma unroll
    for (int j = 0; j < P; ++j) {
        long o = base + (long)j * DC;
        kb0[j] = kk[o]; vb0[j] = (float)vv[o]; rb0[j] = (float)rr[o];
    }
    for (int t0 = 0; t0 < LC; t0 += 2 * P) {
#pragma unroll
        for (int j = 0; j < P; ++j) {
            long o = base + (long)(t0 + P + j) * DC;
            kb1[j] = kk[o]; vb1[j] = (float)vv[o]; rb1[j] = (float)rr[o];
        }
#pragma unroll
        for (int j = 0; j < P; ++j) step(kb0[j], vb0[j], rb0[j], t0 + j);
        if (t0 + 2 * P < LC) {
#pragma unroll
            for (int j = 0; j < P; ++j) {
                long o = base + (long)(t0 + 2 * P + j) * DC;
                kb0[j] = kk[o]; vb0[j] = (float)vv[o]; rb0[j] = (float)rr[o];
            }
        }
#pragma unroll
        for (int j = 0; j < P; ++j) step(kb1[j], vb1[j], rb1[j], t0 + P + j);
    }
}

// ---------------------------------------------------------------------------
extern "C" void kernel_launch(void* const* d_in, const int* in_sizes, int n_in,
                              void* d_out, int out_size, void* d_ws, size_t ws_size,
                              hipStream_t stream) {
    const float* x  = (const float*)d_in[0];
    const float* td = (const float*)d_in[1];
    const float* tf = (const float*)d_in[2];
    const float* mk = (const float*)d_in[3];
    const float* mv = (const float*)d_in[4];
    const float* mr = (const float*)d_in[5];
    const float* Wk = (const float*)d_in[6];
    const float* Wv = (const float*)d_in[7];
    const float* Wr = (const float*)d_in[8];
    const float* Wo = (const float*)d_in[9];
    float* out = (float*)d_out;

    const int D = DC;
    const int T = TC;
    const long total = (long)in_sizes[0];         // B*T*D = 16.7M
    const int M = BnC * T;                        // 8192
    const long DD = DDC;
    const int S = BDC * CC;

    // --- workspace layout ---
    // kf lives in d_out (dead until the final GEMM): the merged gemm3 runs
    // k concurrently with v/r, so the old xmv/xmr overlay would race.
    char* p = (char*)d_ws;
    __bf16* xmk = (__bf16*)p;            p += total * 2;   // dead after gemm3
    __bf16* xmv = (__bf16*)p;            p += total * 2;   // dead after gemm3
    __bf16* xmr = (__bf16*)p;            p += total * 2;   // dead after gemm3
    __bf16* wkb = (__bf16*)p;            p += DD * 2;      // dead after gemm3
    __bf16* wvb = (__bf16*)p;            p += DD * 2;      // dead after gemm3
    __bf16* wrb = (__bf16*)p;            p += DD * 2;      // dead after gemm3
    __bf16* wob = (__bf16*)p;            p += DD * 2;      // live till end
    __bf16* vb  = (__bf16*)p;            p += total * 2;
    __bf16* rb  = (__bf16*)p;            p += total * 2;

    float*  kf = (float*)d_out;          // 64 MB scratch over the output buf
    __bf16* xo = xmk;                    // pass2 output over dead xmk
    float*  st = (float*)wkb;            // 6.3 MB scan state over dead wkb
    float *al = st, *bl = st + S, *el = st + 2 * S;

    unsigned cvtBlocks = (unsigned)((4 * DD / 8 + 255) / 256);
    unsigned mixBlocks = (unsigned)((total / 8 + 255) / 256);
    dim3 prepGrid(cvtBlocks + mixBlocks);
    dim3 gemm3Grid(D / BN, M / BM, 3);            // (16, 64, 3)
    dim3 gemmGrid(D / BN, M / BM);                // (16, 64)
    dim3 p12Grid((S + 255) / 256);                // 2048 blocks
    dim3 cmbGrid((BDC + 255) / 256);              // 32 blocks

    prep_kernel<<<prepGrid, 256, 0, stream>>>(Wk, Wv, Wr, Wo, wkb, wvb, wrb, wob,
                                              cvtBlocks,
                                              x, mk, mv, mr, xmk, xmv, xmr,
                                              total);

    gemm3<<<gemm3Grid, 256, 0, stream>>>(xmv, xmr, xmk, wvb, wrb, wkb,
                                         vb, rb, kf, M, D, D);

    wkv_pass1<<<p12Grid, 256, 0, stream>>>(kf, vb, td, al, bl, el);
    wkv_combine<<<cmbGrid, 256, 0, stream>>>(al, bl, el, td);
    wkv_pass2<<<p12Grid, 256, 0, stream>>>(kf, vb, rb, td, tf, al, bl, el, xo);

    gemm_bt<float><<<gemmGrid, 256, 0, stream>>>(xo, wob, out, M, D, D);
}